// Round 3
// baseline (2157.454 us; speedup 1.0000x reference)
//
#include <hip/hip_runtime.h>
#include <hip/hip_bf16.h>
#include <math.h>

typedef __bf16 bf16_t;
typedef __bf16 bf16x8 __attribute__((ext_vector_type(8)));
typedef float f32x16 __attribute__((ext_vector_type(16)));

#define MFMA32(a, b, c) __builtin_amdgcn_mfma_f32_32x32x16_bf16((a), (b), (c), 0, 0, 0)

// ---- workspace offsets (bytes) ----
#define W1IH_P  (0)
#define W1HH_P  (32*1024)
#define W2IHA_P (544*1024)
#define W2IHB_P (576*1024)
#define W2HH_P  (1088*1024)
#define FC1_P   (1600*1024)
#define FC2_P   (2112*1024)
#define FC3_P   (4160*1024)
#define FC4_P   (5184*1024)
#define BIAS1_P (5440*1024)
#define BIAS2_P (5444*1024)
#define XPAD_P  (5448*1024)   // 128 blocks * 50 v * 64 lanes * 16B = 6.55 MB

// ---- LDS regions (bytes), 64 KB total ----
#define HB0_OFF   0
#define HB1_OFF   16384
#define MB_OFF    0
#define XMLP_OFF  32768

__device__ __forceinline__ float sigm(float x) {
    return __builtin_amdgcn_rcpf(1.0f + __expf(-x));
}
__device__ __forceinline__ float tanh_fast(float x) {
    return 2.0f * __builtin_amdgcn_rcpf(1.0f + __expf(-2.0f * x)) - 1.0f;
}

// Pack an LSTM weight [1024 x ld] (gate-major rows) into per-wave fragment stream:
// dst[w][kk][g][lane][i] = bf16(src[(g*256 + w*32 + lane%32)*ld + k_off + kk*16 + 8*(lane/32)+i])
__global__ void pack_gate(const float* __restrict__ src, bf16_t* __restrict__ dst,
                          int K_src, int n_kk, int k_off, int ld)
{
    int N = 8 * n_kk * 4 * 64 * 8;
    for (int idx = blockIdx.x * blockDim.x + threadIdx.x; idx < N; idx += gridDim.x * blockDim.x) {
        int i = idx & 7;
        int lane = (idx >> 3) & 63;
        int g = (idx >> 9) & 3;
        int t2 = idx >> 11;            // w*n_kk + kk
        int kk = t2 % n_kk;
        int w = t2 / n_kk;
        int k_local = kk * 16 + ((lane >> 5) << 3) + i;
        int row = g * 256 + w * 32 + (lane & 31);
        float v = (k_local < K_src) ? src[(size_t)row * ld + k_off + k_local] : 0.0f;
        dst[idx] = (bf16_t)v;
    }
}

// Pack MLP weight [Nout x K] row-major: dst[w][kk][nt][lane][i]
__global__ void pack_mlp(const float* __restrict__ src, bf16_t* __restrict__ dst, int Nout, int K)
{
    int ncw = Nout >> 3;
    int nnt = ncw >> 5;
    int nkk = K >> 4;
    int N = Nout * K;
    for (int idx = blockIdx.x * blockDim.x + threadIdx.x; idx < N; idx += gridDim.x * blockDim.x) {
        int i = idx & 7;
        int lane = (idx >> 3) & 63;
        int t2 = idx >> 9;
        int nt = t2 % nnt; t2 /= nnt;
        int kk = t2 % nkk;
        int w  = t2 / nkk;
        int row = w * ncw + nt * 32 + (lane & 31);
        int k = kk * 16 + ((lane >> 5) << 3) + i;
        dst[idx] = (bf16_t)src[(size_t)row * K + k];
    }
}

// Pack state [4096 x 750] into per-block A-fragment streams:
// dst[b32][v][lane][i] = bf16(state[(b32*32 + lane%32)*750 + v*15 + 8*(lane/32)+i]), k=15 -> 0
__global__ void pack_x(const float* __restrict__ src, bf16_t* __restrict__ dst)
{
    int N = 128 * 50 * 64 * 8;
    for (int idx = blockIdx.x * blockDim.x + threadIdx.x; idx < N; idx += gridDim.x * blockDim.x) {
        int i = idx & 7;
        int lane = (idx >> 3) & 63;
        int v = (idx >> 9) % 50;
        int b32 = (idx >> 9) / 50;
        int k = ((lane >> 5) << 3) + i;
        int row = b32 * 32 + (lane & 31);
        float val = (k < 15) ? src[(size_t)row * 750 + v * 15 + k] : 0.0f;
        dst[idx] = (bf16_t)val;
    }
}

__global__ void bias_combine(const float* __restrict__ a, const float* __restrict__ b,
                             float* __restrict__ dst, int n)
{
    int i = blockIdx.x * blockDim.x + threadIdx.x;
    if (i < n) dst[i] = a[i] + b[i];
}

// In-place-safe MLP layer: reads ALL input A-frags while accumulating, then
// barriers, then writes output A-frags (outb may alias inb).
template <int NT, int NKK>
__device__ __forceinline__ void mlp_layer(const char* __restrict__ inb, char* __restrict__ outb,
                                          const bf16x8* __restrict__ wp, const float* __restrict__ bias,
                                          int wid, int lane)
{
    const int l32 = lane & 31;
    const int lhi = lane >> 5;
    f32x16 acc[NT];
#pragma unroll
    for (int nt = 0; nt < NT; nt++) {
        float bv = bias[wid * (NT * 32) + nt * 32 + l32];
#pragma unroll
        for (int r = 0; r < 16; r++) acc[nt][r] = bv;
    }
#pragma unroll 4
    for (int kk = 0; kk < NKK; kk++) {
        bf16x8 a = *(const bf16x8*)(inb + kk * 1024 + lane * 16);
#pragma unroll
        for (int nt = 0; nt < NT; nt++)
            acc[nt] = MFMA32(a, wp[(kk * NT + nt) * 64 + lane], acc[nt]);
    }
    __syncthreads();   // all reads done before any in-place writes
#pragma unroll
    for (int nt = 0; nt < NT; nt++) {
        int j = wid * (NT * 32) + nt * 32 + l32;
        int basea = (j >> 4) * 1024 + ((j >> 3) & 1) * 512 + (j & 7) * 2;
#pragma unroll
        for (int r = 0; r < 16; r++) {
            float v = fmaxf(acc[nt][r], 0.0f);
            int row = (r & 3) + 8 * (r >> 2) + 4 * lhi;
            *(bf16_t*)(outb + basea + row * 16) = (bf16_t)v;
        }
    }
}

__launch_bounds__(512, 2)
__global__ void actor_main(const char* __restrict__ ws,
                           const float* __restrict__ fc1_b, const float* __restrict__ fc2_b,
                           const float* __restrict__ fc3_b, const float* __restrict__ fc4_b,
                           const float* __restrict__ piW, const float* __restrict__ pib_p,
                           float* __restrict__ out)
{
    __shared__ __align__(16) char smem[65536];
    const int tid = threadIdx.x;
    const int lane = tid & 63;
    const int wid = tid >> 6;
    const int l32 = lane & 31;
    const int lhi = lane >> 5;
    const int row0 = blockIdx.x * 32;

    const float* bias1 = (const float*)(ws + BIAS1_P);
    const float* bias2 = (const float*)(ws + BIAS2_P);
    const char* xp = ws + XPAD_P + (size_t)blockIdx.x * 51200;  // 50 * 1024B
    const int jcell = wid * 32 + l32;   // this lane's cell column (0..255)
    const int hw_base = (jcell >> 4) * 1024 + ((jcell >> 3) & 1) * 512 + (jcell & 7) * 2;

    {
        int* z = (int*)(smem + HB0_OFF);
        for (int i = tid; i < 4096; i += 512) z[i] = 0;
    }
    __syncthreads();

    // ===================== LSTM 1 =====================
    f32x16 c1;
#pragma unroll
    for (int r = 0; r < 16; r++) c1[r] = 0.0f;

    float b1r[4];
#pragma unroll
    for (int g = 0; g < 4; g++) b1r[g] = bias1[g * 256 + jcell];

    const bf16x8* w1ih = (const bf16x8*)(ws + W1IH_P) + wid * 256 + lane;
    const bf16x8* w1hh = (const bf16x8*)(ws + W1HH_P) + wid * 4096 + lane;

    // hold Wih (4 frags) + Whh kk 0..7 (32 frags) in registers: 144 VGPRs
    bf16x8 wih_r[4];
#pragma unroll
    for (int g = 0; g < 4; g++) wih_r[g] = w1ih[g * 64];
    bf16x8 whh_r[8][4];
#pragma unroll
    for (int kk = 0; kk < 8; kk++)
#pragma unroll
        for (int g = 0; g < 4; g++) whh_r[kk][g] = w1hh[(kk * 4 + g) * 64];

    int cur = HB0_OFF, nxt = HB1_OFF;
    for (int t = 0; t < 50; t++) {
        const char* hb = smem + cur;
        bf16x8 ax = *(const bf16x8*)(xp + t * 1024 + lane * 16);

        // ---- pass 1: gates i (0), g~ (2) ----
        f32x16 ai, ag;
#pragma unroll
        for (int r = 0; r < 16; r++) { ai[r] = b1r[0]; ag[r] = b1r[2]; }
        ai = MFMA32(ax, wih_r[0], ai);
        ag = MFMA32(ax, wih_r[2], ag);
#pragma unroll
        for (int kk = 0; kk < 8; kk++) {
            bf16x8 ah = *(const bf16x8*)(hb + kk * 1024 + lane * 16);
            ai = MFMA32(ah, whh_r[kk][0], ai);
            ag = MFMA32(ah, whh_r[kk][2], ag);
        }
#pragma unroll
        for (int kk = 8; kk < 16; kk++) {
            bf16x8 ah = *(const bf16x8*)(hb + kk * 1024 + lane * 16);
            ai = MFMA32(ah, w1hh[(kk * 4 + 0) * 64], ai);
            ag = MFMA32(ah, w1hh[(kk * 4 + 2) * 64], ag);
        }
        f32x16 ig;
#pragma unroll
        for (int r = 0; r < 16; r++) ig[r] = sigm(ai[r]) * tanh_fast(ag[r]);

        // ---- pass 2: gates f (1), o (3) ----
        f32x16 af, ao;
#pragma unroll
        for (int r = 0; r < 16; r++) { af[r] = b1r[1]; ao[r] = b1r[3]; }
        af = MFMA32(ax, wih_r[1], af);
        ao = MFMA32(ax, wih_r[3], ao);
#pragma unroll
        for (int kk = 0; kk < 8; kk++) {
            bf16x8 ah = *(const bf16x8*)(hb + kk * 1024 + lane * 16);
            af = MFMA32(ah, whh_r[kk][1], af);
            ao = MFMA32(ah, whh_r[kk][3], ao);
        }
#pragma unroll
        for (int kk = 8; kk < 16; kk++) {
            bf16x8 ah = *(const bf16x8*)(hb + kk * 1024 + lane * 16);
            af = MFMA32(ah, w1hh[(kk * 4 + 1) * 64], af);
            ao = MFMA32(ah, w1hh[(kk * 4 + 3) * 64], ao);
        }

        // ---- cell update ----
#pragma unroll
        for (int r = 0; r < 16; r++) {
            float c = sigm(af[r]) * c1[r] + ig[r];
            c1[r] = c;
            float h = sigm(ao[r]) * tanh_fast(c);
            int row = (r & 3) + 8 * (r >> 2) + 4 * lhi;
            *(bf16_t*)(smem + nxt + hw_base + row * 16) = (bf16_t)h;
        }
        __syncthreads();
        int tmp = cur; cur = nxt; nxt = tmp;
    }

    // ===================== MLP (in-place in MB, 64KB) =====================
    // after 50 (even) swaps cur == HB0_OFF == 0; fc1 reads 0..16K, writes 0..64K (internal barrier)
    mlp_layer<4, 16>(smem + cur, smem + MB_OFF,
                     (const bf16x8*)(ws + FC1_P) + wid * (16 * 4 * 64), fc1_b, wid, lane);
    __syncthreads();
    mlp_layer<4, 64>(smem + MB_OFF, smem + MB_OFF,
                     (const bf16x8*)(ws + FC2_P) + wid * (64 * 4 * 64), fc2_b, wid, lane);
    __syncthreads();
    mlp_layer<2, 64>(smem + MB_OFF, smem + MB_OFF,
                     (const bf16x8*)(ws + FC3_P) + wid * (64 * 2 * 64), fc3_b, wid, lane);
    __syncthreads();
    mlp_layer<1, 32>(smem + MB_OFF, smem + XMLP_OFF,
                     (const bf16x8*)(ws + FC4_P) + wid * (32 * 1 * 64), fc4_b, wid, lane);
    __syncthreads();

    // ========== LSTM2 hoisted base: bias2 + xmlp @ W2ih[:,15:]^T (constant over t) ==========
    f32x16 base[4];
#pragma unroll
    for (int g = 0; g < 4; g++) {
        float bv = bias2[g * 256 + jcell];
#pragma unroll
        for (int r = 0; r < 16; r++) base[g][r] = bv;
    }
    {
        const bf16x8* w2b = (const bf16x8*)(ws + W2IHB_P) + wid * 4096 + lane;
#pragma unroll 4
        for (int kk = 0; kk < 16; kk++) {
            bf16x8 a = *(const bf16x8*)(smem + XMLP_OFF + kk * 1024 + lane * 16);
#pragma unroll
            for (int g = 0; g < 4; g++)
                base[g] = MFMA32(a, w2b[(kk * 4 + g) * 64], base[g]);
        }
    }
    // XMLP (32K..48K) disjoint from HB0/HB1 (0..32K): zeroing below is safe.

    {
        int* z = (int*)(smem + HB0_OFF);
        for (int i = tid; i < 4096; i += 512) z[i] = 0;
    }
    __syncthreads();

    // ===================== LSTM 2 + pi head =====================
    f32x16 c2;
#pragma unroll
    for (int r = 0; r < 16; r++) c2[r] = 0.0f;

    const bf16x8* w2a = (const bf16x8*)(ws + W2IHA_P) + wid * 256 + lane;
    const bf16x8* w2hh = (const bf16x8*)(ws + W2HH_P) + wid * 4096 + lane;

    // hold Wih-a (4 frags) + Whh kk 0..3 (16 frags): 80 VGPRs (base holds 64 more)
    bf16x8 w2a_r[4];
#pragma unroll
    for (int g = 0; g < 4; g++) w2a_r[g] = w2a[g * 64];
    bf16x8 w2hh_r[4][4];
#pragma unroll
    for (int kk = 0; kk < 4; kk++)
#pragma unroll
        for (int g = 0; g < 4; g++) w2hh_r[kk][g] = w2hh[(kk * 4 + g) * 64];

    const int prow = tid >> 4;   // 0..31
    const int pkk = tid & 15;    // 0..15
    float pw[16];
#pragma unroll
    for (int q = 0; q < 16; q++) pw[q] = piW[pkk * 16 + q];
    const float pib = pib_p[0];

    cur = HB0_OFF; nxt = HB1_OFF;
    for (int t = 0; t < 50; t++) {
        const char* hb = smem + cur;
        bf16x8 ax = *(const bf16x8*)(xp + t * 1024 + lane * 16);

        // ---- pass 1: gates i (0), g~ (2) ----
        f32x16 ai = base[0], ag = base[2];
        ai = MFMA32(ax, w2a_r[0], ai);
        ag = MFMA32(ax, w2a_r[2], ag);
#pragma unroll
        for (int kk = 0; kk < 4; kk++) {
            bf16x8 ah = *(const bf16x8*)(hb + kk * 1024 + lane * 16);
            ai = MFMA32(ah, w2hh_r[kk][0], ai);
            ag = MFMA32(ah, w2hh_r[kk][2], ag);
        }
#pragma unroll
        for (int kk = 4; kk < 16; kk++) {
            bf16x8 ah = *(const bf16x8*)(hb + kk * 1024 + lane * 16);
            ai = MFMA32(ah, w2hh[(kk * 4 + 0) * 64], ai);
            ag = MFMA32(ah, w2hh[(kk * 4 + 2) * 64], ag);
        }
        f32x16 ig;
#pragma unroll
        for (int r = 0; r < 16; r++) ig[r] = sigm(ai[r]) * tanh_fast(ag[r]);

        // ---- pass 2: gates f (1), o (3) ----
        f32x16 af = base[1], ao = base[3];
        af = MFMA32(ax, w2a_r[1], af);
        ao = MFMA32(ax, w2a_r[3], ao);
#pragma unroll
        for (int kk = 0; kk < 4; kk++) {
            bf16x8 ah = *(const bf16x8*)(hb + kk * 1024 + lane * 16);
            af = MFMA32(ah, w2hh_r[kk][1], af);
            ao = MFMA32(ah, w2hh_r[kk][3], ao);
        }
#pragma unroll
        for (int kk = 4; kk < 16; kk++) {
            bf16x8 ah = *(const bf16x8*)(hb + kk * 1024 + lane * 16);
            af = MFMA32(ah, w2hh[(kk * 4 + 1) * 64], af);
            ao = MFMA32(ah, w2hh[(kk * 4 + 3) * 64], ao);
        }

        // ---- cell update ----
#pragma unroll
        for (int r = 0; r < 16; r++) {
            float c = sigm(af[r]) * c2[r] + ig[r];
            c2[r] = c;
            float h = sigm(ao[r]) * tanh_fast(c);
            int row = (r & 3) + 8 * (r >> 2) + 4 * lhi;
            *(bf16_t*)(smem + nxt + hw_base + row * 16) = (bf16_t)h;
        }
        __syncthreads();

        // pi head on h2_t (just written to nxt): 16 threads per row, fp32 dot
        bf16x8 h0 = *(const bf16x8*)(smem + nxt + pkk * 1024 + prow * 16);
        bf16x8 h1v = *(const bf16x8*)(smem + nxt + pkk * 1024 + (prow + 32) * 16);
        float s = 0.0f;
#pragma unroll
        for (int q = 0; q < 8; q++) s += (float)h0[q] * pw[q] + (float)h1v[q] * pw[8 + q];
        s += __shfl_xor(s, 1, 16);
        s += __shfl_xor(s, 2, 16);
        s += __shfl_xor(s, 4, 16);
        s += __shfl_xor(s, 8, 16);
        if (pkk == 0) out[(size_t)(row0 + prow) * 50 + t] = tanh_fast(s + pib);

        int tmp = cur; cur = nxt; nxt = tmp;
    }
}

extern "C" void kernel_launch(void* const* d_in, const int* in_sizes, int n_in,
                              void* d_out, int out_size, void* d_ws, size_t ws_size,
                              hipStream_t stream) {
    (void)in_sizes; (void)n_in; (void)out_size; (void)ws_size;
    const float* state   = (const float*)d_in[0];
    const float* l1_Wih  = (const float*)d_in[1];
    const float* l1_Whh  = (const float*)d_in[2];
    const float* l1_bih  = (const float*)d_in[3];
    const float* l1_bhh  = (const float*)d_in[4];
    const float* fc1_W   = (const float*)d_in[5];
    const float* fc1_b   = (const float*)d_in[6];
    const float* fc2_W   = (const float*)d_in[7];
    const float* fc2_b   = (const float*)d_in[8];
    const float* fc3_W   = (const float*)d_in[9];
    const float* fc3_b   = (const float*)d_in[10];
    const float* fc4_W   = (const float*)d_in[11];
    const float* fc4_b   = (const float*)d_in[12];
    const float* l2_Wih  = (const float*)d_in[13];
    const float* l2_Whh  = (const float*)d_in[14];
    const float* l2_bih  = (const float*)d_in[15];
    const float* l2_bhh  = (const float*)d_in[16];
    const float* pi_W    = (const float*)d_in[17];
    const float* pi_b    = (const float*)d_in[18];
    char* ws = (char*)d_ws;
    float* out = (float*)d_out;

    pack_gate<<<256, 256, 0, stream>>>(l1_Wih, (bf16_t*)(ws + W1IH_P), 15, 1, 0, 15);
    pack_gate<<<256, 256, 0, stream>>>(l1_Whh, (bf16_t*)(ws + W1HH_P), 256, 16, 0, 256);
    pack_gate<<<256, 256, 0, stream>>>(l2_Wih, (bf16_t*)(ws + W2IHA_P), 15, 1, 0, 271);
    pack_gate<<<256, 256, 0, stream>>>(l2_Wih, (bf16_t*)(ws + W2IHB_P), 256, 16, 15, 271);
    pack_gate<<<256, 256, 0, stream>>>(l2_Whh, (bf16_t*)(ws + W2HH_P), 256, 16, 0, 256);
    pack_mlp<<<512, 256, 0, stream>>>(fc1_W, (bf16_t*)(ws + FC1_P), 1024, 256);
    pack_mlp<<<512, 256, 0, stream>>>(fc2_W, (bf16_t*)(ws + FC2_P), 1024, 1024);
    pack_mlp<<<512, 256, 0, stream>>>(fc3_W, (bf16_t*)(ws + FC3_P), 512, 1024);
    pack_mlp<<<512, 256, 0, stream>>>(fc4_W, (bf16_t*)(ws + FC4_P), 256, 512);
    pack_x<<<512, 256, 0, stream>>>(state, (bf16_t*)(ws + XPAD_P));
    bias_combine<<<4, 256, 0, stream>>>(l1_bih, l1_bhh, (float*)(ws + BIAS1_P), 1024);
    bias_combine<<<4, 256, 0, stream>>>(l2_bih, l2_bhh, (float*)(ws + BIAS2_P), 1024);

    actor_main<<<128, 512, 0, stream>>>(ws, fc1_b, fc2_b, fc3_b, fc4_b,
                                        pi_W, pi_b, out);
}

// Round 4
// 1323.201 us; speedup vs baseline: 1.6305x; 1.6305x over previous
//
#include <hip/hip_runtime.h>
#include <hip/hip_bf16.h>
#include <math.h>

typedef __bf16 bf16_t;
typedef __bf16 bf16x4 __attribute__((ext_vector_type(4)));
typedef __bf16 bf16x8 __attribute__((ext_vector_type(8)));
typedef float f32x4 __attribute__((ext_vector_type(4)));

#define MFMA16(a, b, c) __builtin_amdgcn_mfma_f32_16x16x32_bf16((a), (b), (c), 0, 0, 0)

// ---- workspace offsets (bytes) ----
#define W1IH_P  0
#define W1HH_P  65536
#define W2IHA_P 589824
#define W2IHB_P 655360
#define W2HH_P  1179648
#define FC1_P   1703936
#define FC2_P   2228224
#define FC3_P   4325376
#define FC4_P   5373952
#define BIAS1_P 5636096
#define BIAS2_P 5640192
#define XPAD_P  5644288   // 256 blocks * 50 * 32 lanes * 16B = 6.55 MB -> ends ~12.2MB

// ---- LDS regions (bytes), 56 KB static ----
#define HB0   0
#define HB1   8192
#define MB    16384
#define XMLP  49152

__device__ __forceinline__ float sigm(float x) {
    return __builtin_amdgcn_rcpf(1.0f + __expf(-x));
}
__device__ __forceinline__ float tanh_fast(float x) {
    return 2.0f * __builtin_amdgcn_rcpf(1.0f + __expf(-2.0f * x)) - 1.0f;
}

// LSTM weight pack: per-wave B-frag stream for 16x16x32.
// dst bf16 idx = ((w*(n_kt*4) + kt*4 + g)*64 + lane)*8 + i
// value = src[(g*256 + w*16 + (lane&15))*ld + k_off + kt*32 + 8*(lane>>4) + i]  (0 if k>=K_src)
__device__ __forceinline__ void pack_gate_elem(const float* __restrict__ src, bf16_t* __restrict__ dst,
                                               int idx, int n_kt, int k_off, int K_src, int ld)
{
    int i = idx & 7;
    int lane = (idx >> 3) & 63;
    int g = (idx >> 9) & 3;
    int t2 = idx >> 11;
    int kt = t2 % n_kt;
    int w  = t2 / n_kt;
    int k_local = kt * 32 + ((lane >> 4) << 3) + i;
    int row = g * 256 + w * 16 + (lane & 15);
    float v = (k_local < K_src) ? src[(size_t)row * ld + k_off + k_local] : 0.0f;
    dst[idx] = (bf16_t)v;
}

__global__ void pack_lstm_all(const float* __restrict__ l1_Wih, const float* __restrict__ l1_Whh,
                              const float* __restrict__ l2_Wih, const float* __restrict__ l2_Whh,
                              const float* __restrict__ l1_bih, const float* __restrict__ l1_bhh,
                              const float* __restrict__ l2_bih, const float* __restrict__ l2_bhh,
                              char* __restrict__ ws)
{
    const int NTOT = 854016;
    for (int idx = blockIdx.x * blockDim.x + threadIdx.x; idx < NTOT; idx += gridDim.x * blockDim.x) {
        int j = idx;
        if (j < 32768)  { pack_gate_elem(l1_Wih, (bf16_t*)(ws + W1IH_P),  j, 1, 0, 15, 15);   continue; }
        j -= 32768;
        if (j < 262144) { pack_gate_elem(l1_Whh, (bf16_t*)(ws + W1HH_P),  j, 8, 0, 256, 256); continue; }
        j -= 262144;
        if (j < 32768)  { pack_gate_elem(l2_Wih, (bf16_t*)(ws + W2IHA_P), j, 1, 0, 15, 271);  continue; }
        j -= 32768;
        if (j < 262144) { pack_gate_elem(l2_Wih, (bf16_t*)(ws + W2IHB_P), j, 8, 15, 256, 271);continue; }
        j -= 262144;
        if (j < 262144) { pack_gate_elem(l2_Whh, (bf16_t*)(ws + W2HH_P),  j, 8, 0, 256, 256); continue; }
        j -= 262144;
        if (j < 1024)   { ((float*)(ws + BIAS1_P))[j] = l1_bih[j] + l1_bhh[j]; continue; }
        j -= 1024;
        ((float*)(ws + BIAS2_P))[j] = l2_bih[j] + l2_bhh[j];
    }
}

// MLP weight pack: dst bf16 idx = ((w*NKT*CT + kt*CT + ct)*64 + lane)*8 + i
// value = src[((w*CT+ct)*16 + (lane&15))*K + kt*32 + 8*(lane>>4) + i]
__device__ __forceinline__ void pack_mlp_elem(const float* __restrict__ src, bf16_t* __restrict__ dst,
                                              int idx, int CT, int NKT, int K)
{
    int i = idx & 7;
    int lane = (idx >> 3) & 63;
    int r = idx >> 9;
    int ct = r % CT; r /= CT;
    int kt = r % NKT;
    int w  = r / NKT;
    int col = (w * CT + ct) * 16 + (lane & 15);
    int k = kt * 32 + ((lane >> 4) << 3) + i;
    dst[idx] = (bf16_t)src[(size_t)col * K + k];
}

__global__ void pack_mlp_all(const float* __restrict__ fc1, const float* __restrict__ fc2,
                             const float* __restrict__ fc3, const float* __restrict__ fc4,
                             char* __restrict__ ws)
{
    const int NTOT = 1966080;
    for (int idx = blockIdx.x * blockDim.x + threadIdx.x; idx < NTOT; idx += gridDim.x * blockDim.x) {
        int j = idx;
        if (j < 262144)  { pack_mlp_elem(fc1, (bf16_t*)(ws + FC1_P), j, 4, 8, 256);   continue; }
        j -= 262144;
        if (j < 1048576) { pack_mlp_elem(fc2, (bf16_t*)(ws + FC2_P), j, 4, 32, 1024); continue; }
        j -= 1048576;
        if (j < 524288)  { pack_mlp_elem(fc3, (bf16_t*)(ws + FC3_P), j, 2, 32, 1024); continue; }
        j -= 524288;
        pack_mlp_elem(fc4, (bf16_t*)(ws + FC4_P), j, 1, 16, 512);
    }
}

// x pack: A-frags (16 rows x 32 k, only lanes 0..31 stored since k<16).
// dst idx = ((b*50 + v)*32 + l5)*8 + i ; value = state[(b*16 + (l5&15))*750 + v*15 + 8*(l5>>4)+i] (0 if k>=15)
__global__ void pack_x16(const float* __restrict__ state, bf16_t* __restrict__ dst)
{
    const int NTOT = 3276800;
    for (int idx = blockIdx.x * blockDim.x + threadIdx.x; idx < NTOT; idx += gridDim.x * blockDim.x) {
        int i = idx & 7;
        int l5 = (idx >> 3) & 31;
        int v = (idx >> 8) % 50;
        int b = (idx >> 8) / 50;
        int k = ((l5 >> 4) << 3) + i;
        int row = b * 16 + (l5 & 15);
        float val = (k < 15) ? state[(size_t)row * 750 + v * 15 + k] : 0.0f;
        dst[idx] = (bf16_t)val;
    }
}

// In-place-safe MLP layer (16 waves, 16 rows): read all input frags, barrier, write output frags.
template <int CT, int NKT>
__device__ __forceinline__ void mlp16(const char* __restrict__ inb, char* __restrict__ outb,
                                      const bf16x8* __restrict__ wp, const float* __restrict__ bias,
                                      int w, int lane)
{
    const int l15 = lane & 15;
    f32x4 acc[CT];
#pragma unroll
    for (int ct = 0; ct < CT; ct++) {
        float bv = bias[(w * CT + ct) * 16 + l15];
        acc[ct] = (f32x4){bv, bv, bv, bv};
    }
#pragma unroll 4
    for (int kt = 0; kt < NKT; kt++) {
        bf16x8 a = *(const bf16x8*)(inb + kt * 1024 + lane * 16);
#pragma unroll
        for (int ct = 0; ct < CT; ct++)
            acc[ct] = MFMA16(a, wp[(kt * CT + ct) * 64 + lane], acc[ct]);
    }
    __syncthreads();   // all reads complete before in-place writes
#pragma unroll
    for (int ct = 0; ct < CT; ct++) {
        int j = (w * CT + ct) * 16 + l15;
#pragma unroll
        for (int r = 0; r < 4; r++) {
            float v = fmaxf(acc[ct][r], 0.0f);
            int lrow = ((lane >> 4) << 2) + r + (((j & 31) >> 3) << 4);
            *(bf16_t*)(outb + ((j >> 5) << 10) + lrow * 16 + ((j & 7) << 1)) = (bf16_t)v;
        }
    }
}

__launch_bounds__(1024, 1)
__global__ void actor_main(const char* __restrict__ ws,
                           const float* __restrict__ fc1_b, const float* __restrict__ fc2_b,
                           const float* __restrict__ fc3_b, const float* __restrict__ fc4_b,
                           const float* __restrict__ piW, const float* __restrict__ pib_p,
                           float* __restrict__ out)
{
    __shared__ __align__(16) char smem[57344];
    const int tid = threadIdx.x;
    const int lane = tid & 63;
    const int w = tid >> 6;           // wave id; also the pi batch-row this wave reduces
    const int l15 = lane & 15;
    const int row0 = blockIdx.x * 16;

    const float* bias1 = (const float*)(ws + BIAS1_P);
    const float* bias2 = (const float*)(ws + BIAS2_P);
    const char* xp = ws + XPAD_P + (size_t)blockIdx.x * (50 * 512);

    // h-write address: cell j = 16w + l15, rows (lane>>4)*4 + r
    const int klocal = ((w & 1) << 4) + l15;
    const int base_l = ((lane >> 4) << 2) + ((klocal >> 3) << 4);
    const int hw_byte = ((w >> 1) << 10) + (base_l << 4) + ((l15 & 7) << 1);

    // pi constants: lane handles j = 4*lane .. 4*lane+3 of row w
    const float pib = pib_p[0];
    float pw0, pw1, pw2, pw3;
    {
        const float4 p4 = *(const float4*)(piW + lane * 4);
        pw0 = p4.x; pw1 = p4.y; pw2 = p4.z; pw3 = p4.w;
    }
    const int pi_byte = ((lane >> 3) << 10) + ((w + (((lane >> 1) & 3) << 4)) << 4) + ((lane & 1) << 3);

    // ---- LSTM1 weights -> registers (32+4 frags = 144 VGPR) ----
    bf16x8 wih_r[4], whh_r[8][4];
    {
        const bf16x8* wi = (const bf16x8*)(ws + W1IH_P) + w * (4 * 64);
#pragma unroll
        for (int g = 0; g < 4; g++) wih_r[g] = wi[g * 64 + lane];
        const bf16x8* wh = (const bf16x8*)(ws + W1HH_P) + w * (8 * 4 * 64);
#pragma unroll
        for (int kt = 0; kt < 8; kt++)
#pragma unroll
            for (int g = 0; g < 4; g++) whh_r[kt][g] = wh[(kt * 4 + g) * 64 + lane];
    }
    f32x4 gb[4];
#pragma unroll
    for (int g = 0; g < 4; g++) {
        float bv = bias1[g * 256 + w * 16 + l15];
        gb[g] = (f32x4){bv, bv, bv, bv};
    }

    { int* z = (int*)(smem + HB0); for (int i = tid; i < 2048; i += 1024) z[i] = 0; }
    __syncthreads();

    // ===================== LSTM 1 =====================
    int cur = HB0, nxt = HB1;
    f32x4 cst = (f32x4){0.0f, 0.0f, 0.0f, 0.0f};
    for (int t = 0; t < 50; t++) {
        bf16x8 ax;
#pragma unroll
        for (int q = 0; q < 8; q++) ax[q] = (bf16_t)0.0f;
        if (lane < 32) ax = *(const bf16x8*)(xp + t * 512 + lane * 16);

        f32x4 a0 = gb[0], a1 = gb[1], a2 = gb[2], a3 = gb[3];
        a0 = MFMA16(ax, wih_r[0], a0);
        a1 = MFMA16(ax, wih_r[1], a1);
        a2 = MFMA16(ax, wih_r[2], a2);
        a3 = MFMA16(ax, wih_r[3], a3);
#pragma unroll
        for (int kt = 0; kt < 8; kt++) {
            bf16x8 ah = *(const bf16x8*)(smem + cur + kt * 1024 + lane * 16);
            a0 = MFMA16(ah, whh_r[kt][0], a0);
            a1 = MFMA16(ah, whh_r[kt][1], a1);
            a2 = MFMA16(ah, whh_r[kt][2], a2);
            a3 = MFMA16(ah, whh_r[kt][3], a3);
        }
#pragma unroll
        for (int r = 0; r < 4; r++) {
            float iv = sigm(a0[r]);
            float fv = sigm(a1[r]);
            float gv = tanh_fast(a2[r]);
            float ov = sigm(a3[r]);
            float c = fv * cst[r] + iv * gv;
            cst[r] = c;
            float h = ov * tanh_fast(c);
            *(bf16_t*)(smem + nxt + hw_byte + r * 16) = (bf16_t)h;
        }
        __syncthreads();
        int tmp = cur; cur = nxt; nxt = tmp;
    }
    // h1 frags in smem+cur (HB0, 8KB)

    // ===================== MLP (in-place in MB) =====================
    mlp16<4, 8>(smem + cur, smem + MB, (const bf16x8*)(ws + FC1_P) + w * (8 * 4 * 64), fc1_b, w, lane);
    __syncthreads();
    mlp16<4, 32>(smem + MB, smem + MB, (const bf16x8*)(ws + FC2_P) + w * (32 * 4 * 64), fc2_b, w, lane);
    __syncthreads();
    mlp16<2, 32>(smem + MB, smem + MB, (const bf16x8*)(ws + FC3_P) + w * (32 * 2 * 64), fc3_b, w, lane);
    __syncthreads();
    mlp16<1, 16>(smem + MB, smem + XMLP, (const bf16x8*)(ws + FC4_P) + w * (16 * 1 * 64), fc4_b, w, lane);
    __syncthreads();

    // ---- LSTM2 hoisted base: bias2 + xmlp @ W2ih[:,15:]^T ----
    f32x4 base2[4];
#pragma unroll
    for (int g = 0; g < 4; g++) {
        float bv = bias2[g * 256 + w * 16 + l15];
        base2[g] = (f32x4){bv, bv, bv, bv};
    }
    {
        const bf16x8* wb = (const bf16x8*)(ws + W2IHB_P) + w * (8 * 4 * 64);
#pragma unroll
        for (int kt = 0; kt < 8; kt++) {
            bf16x8 a = *(const bf16x8*)(smem + XMLP + kt * 1024 + lane * 16);
#pragma unroll
            for (int g = 0; g < 4; g++) base2[g] = MFMA16(a, wb[(kt * 4 + g) * 64 + lane], base2[g]);
        }
    }

    // ---- LSTM2 weights -> registers ----
    {
        const bf16x8* wi = (const bf16x8*)(ws + W2IHA_P) + w * (4 * 64);
#pragma unroll
        for (int g = 0; g < 4; g++) wih_r[g] = wi[g * 64 + lane];
        const bf16x8* wh = (const bf16x8*)(ws + W2HH_P) + w * (8 * 4 * 64);
#pragma unroll
        for (int kt = 0; kt < 8; kt++)
#pragma unroll
            for (int g = 0; g < 4; g++) whh_r[kt][g] = wh[(kt * 4 + g) * 64 + lane];
    }

    { int* z = (int*)(smem + HB0); for (int i = tid; i < 2048; i += 1024) z[i] = 0; }
    __syncthreads();

    // ===================== LSTM 2 + pi head =====================
    cur = HB0; nxt = HB1;
    cst = (f32x4){0.0f, 0.0f, 0.0f, 0.0f};
    float* outp = out + (size_t)(row0 + w) * 50;
    for (int t = 0; t < 50; t++) {
        bf16x8 ax;
#pragma unroll
        for (int q = 0; q < 8; q++) ax[q] = (bf16_t)0.0f;
        if (lane < 32) ax = *(const bf16x8*)(xp + t * 512 + lane * 16);

        f32x4 a0 = base2[0], a1 = base2[1], a2 = base2[2], a3 = base2[3];
        a0 = MFMA16(ax, wih_r[0], a0);
        a1 = MFMA16(ax, wih_r[1], a1);
        a2 = MFMA16(ax, wih_r[2], a2);
        a3 = MFMA16(ax, wih_r[3], a3);
#pragma unroll
        for (int kt = 0; kt < 8; kt++) {
            bf16x8 ah = *(const bf16x8*)(smem + cur + kt * 1024 + lane * 16);
            a0 = MFMA16(ah, whh_r[kt][0], a0);
            a1 = MFMA16(ah, whh_r[kt][1], a1);
            a2 = MFMA16(ah, whh_r[kt][2], a2);
            a3 = MFMA16(ah, whh_r[kt][3], a3);
        }
#pragma unroll
        for (int r = 0; r < 4; r++) {
            float iv = sigm(a0[r]);
            float fv = sigm(a1[r]);
            float gv = tanh_fast(a2[r]);
            float ov = sigm(a3[r]);
            float c = fv * cst[r] + iv * gv;
            cst[r] = c;
            float h = ov * tanh_fast(c);
            *(bf16_t*)(smem + nxt + hw_byte + r * 16) = (bf16_t)h;
        }
        __syncthreads();

        // pi head: wave w reduces row w over all 256 cells (4 bf16 per lane)
        bf16x4 hv = *(const bf16x4*)(smem + nxt + pi_byte);
        float s = (float)hv[0] * pw0 + (float)hv[1] * pw1 + (float)hv[2] * pw2 + (float)hv[3] * pw3;
        s += __shfl_xor(s, 1);
        s += __shfl_xor(s, 2);
        s += __shfl_xor(s, 4);
        s += __shfl_xor(s, 8);
        s += __shfl_xor(s, 16);
        s += __shfl_xor(s, 32);
        if (lane == 0) outp[t] = tanh_fast(s + pib);

        int tmp = cur; cur = nxt; nxt = tmp;
    }
}

extern "C" void kernel_launch(void* const* d_in, const int* in_sizes, int n_in,
                              void* d_out, int out_size, void* d_ws, size_t ws_size,
                              hipStream_t stream) {
    (void)in_sizes; (void)n_in; (void)out_size; (void)ws_size;
    const float* state   = (const float*)d_in[0];
    const float* l1_Wih  = (const float*)d_in[1];
    const float* l1_Whh  = (const float*)d_in[2];
    const float* l1_bih  = (const float*)d_in[3];
    const float* l1_bhh  = (const float*)d_in[4];
    const float* fc1_W   = (const float*)d_in[5];
    const float* fc1_b   = (const float*)d_in[6];
    const float* fc2_W   = (const float*)d_in[7];
    const float* fc2_b   = (const float*)d_in[8];
    const float* fc3_W   = (const float*)d_in[9];
    const float* fc3_b   = (const float*)d_in[10];
    const float* fc4_W   = (const float*)d_in[11];
    const float* fc4_b   = (const float*)d_in[12];
    const float* l2_Wih  = (const float*)d_in[13];
    const float* l2_Whh  = (const float*)d_in[14];
    const float* l2_bih  = (const float*)d_in[15];
    const float* l2_bhh  = (const float*)d_in[16];
    const float* pi_W    = (const float*)d_in[17];
    const float* pi_b    = (const float*)d_in[18];
    char* ws = (char*)d_ws;
    float* out = (float*)d_out;

    pack_lstm_all<<<512, 256, 0, stream>>>(l1_Wih, l1_Whh, l2_Wih, l2_Whh,
                                           l1_bih, l1_bhh, l2_bih, l2_bhh, ws);
    pack_mlp_all<<<1024, 256, 0, stream>>>(fc1_W, fc2_W, fc3_W, fc4_W, ws);
    pack_x16<<<1024, 256, 0, stream>>>(state, (bf16_t*)(ws + XPAD_P));

    actor_main<<<256, 1024, 0, stream>>>(ws, fc1_b, fc2_b, fc3_b, fc4_b,
                                         pi_W, pi_b, out);
}

// Round 10
// 861.619 us; speedup vs baseline: 2.5040x; 1.5357x over previous
//
#include <hip/hip_runtime.h>
#include <hip/hip_bf16.h>
#include <math.h>

typedef __bf16 bf16_t;
typedef __bf16 bf16x4 __attribute__((ext_vector_type(4)));
typedef __bf16 bf16x8 __attribute__((ext_vector_type(8)));
typedef float f32x4 __attribute__((ext_vector_type(4)));

#define MFMA(a,b,c) __builtin_amdgcn_mfma_f32_16x16x32_bf16((a),(b),(c),0,0,0)

// ---- ws offsets in bf16 elements ----
#define W1HHR_E 0          // [w8][kt6][cg2][g4][lane64][8]
#define W1HHL_E 196608     // [w8][kk2][cg2][g4][lane64][8]
#define WIH1_E  262144     // [w8][cg2][g4][l32][8]  (k=8*(l5>>4)+i, k>=15 -> 0)
#define W2HHR_E 278528
#define W2HHL_E 475136
#define WIH2_E  540672
#define W2IHB_E 557056     // [w8][kt8][cg2][g4][lane64][8]
#define BIAS1_E 1081344    // f32[1024]
#define BIAS2_E 1083392    // f32[1024]
#define FC1_E   1085440    // [w8][kt8][ct8][lane64][8]
#define FC2_E   1347584    // [w8][kt32][ct8]
#define FC3_E   2396160    // [w8][kt32][ct4]
#define FC4_E   2920448    // [w8][kt16][ct2]
#define XPAD_E  3051520    // [b256][t50][l32][8]

// ---- LDS (bytes) ----
#define WLDS 0             // 128KB: [w8][kk2][cg2][g4][1KB frag]
#define HB   131072        // 8KB: h A-frags, 8 ktiles
#define WIHL 139264        // 16KB: [w8][g4][512B frag] (cg=1 half)
#define LDS_BYTES 155648

__device__ __forceinline__ float sigm(float x) {
    return __builtin_amdgcn_rcpf(1.0f + __expf(-x));
}
__device__ __forceinline__ float tanh_fast(float x) {
    return 2.0f * __builtin_amdgcn_rcpf(1.0f + __expf(-2.0f * x)) - 1.0f;
}
__device__ __forceinline__ bf16x8 zero8() {
    bf16x8 z;
#pragma unroll
    for (int q = 0; q < 8; q++) z[q] = (bf16_t)0.0f;
    return z;
}

// ================= single fused pack kernel =================
__global__ void pack_all(const float* __restrict__ state,
                         const float* __restrict__ w1ih, const float* __restrict__ w1hh,
                         const float* __restrict__ b1i,  const float* __restrict__ b1h,
                         const float* __restrict__ fc1,  const float* __restrict__ fc2,
                         const float* __restrict__ fc3,  const float* __restrict__ fc4,
                         const float* __restrict__ w2ih, const float* __restrict__ w2hh,
                         const float* __restrict__ b2i,  const float* __restrict__ b2h,
                         bf16_t* __restrict__ ws)
{
    const int NTOT = 6326272;
    for (int idx = blockIdx.x * blockDim.x + threadIdx.x; idx < NTOT; idx += gridDim.x * blockDim.x) {
        int j = idx;
        if (j < 196608) {  // W1HHR
            int i = j & 7, lane = (j >> 3) & 63, g = (j >> 9) & 3, cg = (j >> 11) & 1;
            int rem = j >> 12, kt = rem % 6, w = rem / 6;
            int col = g * 256 + w * 32 + cg * 16 + (lane & 15);
            int k = kt * 32 + ((lane >> 4) << 3) + i;
            ws[W1HHR_E + j] = (bf16_t)w1hh[(size_t)col * 256 + k];
            continue;
        }
        j -= 196608;
        if (j < 65536) {   // W1HHL
            int i = j & 7, lane = (j >> 3) & 63, g = (j >> 9) & 3, cg = (j >> 11) & 1;
            int kk = (j >> 12) & 1, w = j >> 13;
            int col = g * 256 + w * 32 + cg * 16 + (lane & 15);
            int k = (6 + kk) * 32 + ((lane >> 4) << 3) + i;
            ws[W1HHL_E + j] = (bf16_t)w1hh[(size_t)col * 256 + k];
            continue;
        }
        j -= 65536;
        if (j < 16384) {   // WIH1
            int i = j & 7, l5 = (j >> 3) & 31, g = (j >> 8) & 3, cg = (j >> 10) & 1, w = j >> 11;
            int col = g * 256 + w * 32 + cg * 16 + (l5 & 15);
            int k = ((l5 >> 4) << 3) + i;
            ws[WIH1_E + j] = (bf16_t)((k < 15) ? w1ih[(size_t)col * 15 + k] : 0.0f);
            continue;
        }
        j -= 16384;
        if (j < 196608) {  // W2HHR
            int i = j & 7, lane = (j >> 3) & 63, g = (j >> 9) & 3, cg = (j >> 11) & 1;
            int rem = j >> 12, kt = rem % 6, w = rem / 6;
            int col = g * 256 + w * 32 + cg * 16 + (lane & 15);
            int k = kt * 32 + ((lane >> 4) << 3) + i;
            ws[W2HHR_E + j] = (bf16_t)w2hh[(size_t)col * 256 + k];
            continue;
        }
        j -= 196608;
        if (j < 65536) {   // W2HHL
            int i = j & 7, lane = (j >> 3) & 63, g = (j >> 9) & 3, cg = (j >> 11) & 1;
            int kk = (j >> 12) & 1, w = j >> 13;
            int col = g * 256 + w * 32 + cg * 16 + (lane & 15);
            int k = (6 + kk) * 32 + ((lane >> 4) << 3) + i;
            ws[W2HHL_E + j] = (bf16_t)w2hh[(size_t)col * 256 + k];
            continue;
        }
        j -= 65536;
        if (j < 16384) {   // WIH2 (first 15 cols of l2_Wih, ld=271)
            int i = j & 7, l5 = (j >> 3) & 31, g = (j >> 8) & 3, cg = (j >> 10) & 1, w = j >> 11;
            int col = g * 256 + w * 32 + cg * 16 + (l5 & 15);
            int k = ((l5 >> 4) << 3) + i;
            ws[WIH2_E + j] = (bf16_t)((k < 15) ? w2ih[(size_t)col * 271 + k] : 0.0f);
            continue;
        }
        j -= 16384;
        if (j < 524288) {  // W2IHB (cols 15..270 of l2_Wih)
            int i = j & 7, lane = (j >> 3) & 63, g = (j >> 9) & 3, cg = (j >> 11) & 1;
            int kt = (j >> 12) & 7, w = j >> 15;
            int col = g * 256 + w * 32 + cg * 16 + (lane & 15);
            int k = kt * 32 + ((lane >> 4) << 3) + i;
            ws[W2IHB_E + j] = (bf16_t)w2ih[(size_t)col * 271 + 15 + k];
            continue;
        }
        j -= 524288;
        if (j < 1024) { ((float*)(ws + BIAS1_E))[j] = b1i[j] + b1h[j]; continue; }
        j -= 1024;
        if (j < 1024) { ((float*)(ws + BIAS2_E))[j] = b2i[j] + b2h[j]; continue; }
        j -= 1024;
        if (j < 262144) {  // FC1: CT=8 NKT=8 K=256
            int i = j & 7, lane = (j >> 3) & 63, t2 = j >> 9;
            int ct = t2 & 7; t2 >>= 3; int kt = t2 & 7, w = t2 >> 3;
            int col = (w * 8 + ct) * 16 + (lane & 15);
            int k = kt * 32 + ((lane >> 4) << 3) + i;
            ws[FC1_E + j] = (bf16_t)fc1[(size_t)col * 256 + k];
            continue;
        }
        j -= 262144;
        if (j < 1048576) { // FC2: CT=8 NKT=32 K=1024
            int i = j & 7, lane = (j >> 3) & 63, t2 = j >> 9;
            int ct = t2 & 7; t2 >>= 3; int kt = t2 & 31, w = t2 >> 5;
            int col = (w * 8 + ct) * 16 + (lane & 15);
            int k = kt * 32 + ((lane >> 4) << 3) + i;
            ws[FC2_E + j] = (bf16_t)fc2[(size_t)col * 1024 + k];
            continue;
        }
        j -= 1048576;
        if (j < 524288) {  // FC3: CT=4 NKT=32 K=1024
            int i = j & 7, lane = (j >> 3) & 63, t2 = j >> 9;
            int ct = t2 & 3; t2 >>= 2; int kt = t2 & 31, w = t2 >> 5;
            int col = (w * 4 + ct) * 16 + (lane & 15);
            int k = kt * 32 + ((lane >> 4) << 3) + i;
            ws[FC3_E + j] = (bf16_t)fc3[(size_t)col * 1024 + k];
            continue;
        }
        j -= 524288;
        if (j < 131072) {  // FC4: CT=2 NKT=16 K=512
            int i = j & 7, lane = (j >> 3) & 63, t2 = j >> 9;
            int ct = t2 & 1; t2 >>= 1; int kt = t2 & 15, w = t2 >> 4;
            int col = (w * 2 + ct) * 16 + (lane & 15);
            int k = kt * 32 + ((lane >> 4) << 3) + i;
            ws[FC4_E + j] = (bf16_t)fc4[(size_t)col * 512 + k];
            continue;
        }
        j -= 131072;
        {                  // XPAD
            int i = j & 7, l5 = (j >> 3) & 31, t2 = j >> 8;
            int t = t2 % 50, b = t2 / 50;
            int row = b * 16 + (l5 & 15);
            int k = ((l5 >> 4) << 3) + i;
            ws[XPAD_E + j] = (bf16_t)((k < 15) ? state[(size_t)row * 750 + t * 15 + k] : 0.0f);
        }
    }
}

// ================= MLP layer (8 waves, out disjoint from in) =================
template <int CT, int NKT>
__device__ __forceinline__ void mlp8(const char* __restrict__ inb, char* __restrict__ outb,
                                     const bf16x8* __restrict__ wp, const float* __restrict__ bias,
                                     int w, int lane)
{
    const int l15 = lane & 15;
    const int lhi = lane >> 4;
    f32x4 acc[CT];
#pragma unroll
    for (int ct = 0; ct < CT; ct++) {
        float bv = bias[(w * CT + ct) * 16 + l15];
        acc[ct] = (f32x4){bv, bv, bv, bv};
    }
#pragma unroll 4
    for (int kt = 0; kt < NKT; kt++) {
        bf16x8 a = *(const bf16x8*)(inb + kt * 1024 + lane * 16);
#pragma unroll
        for (int ct = 0; ct < CT; ct++)
            acc[ct] = MFMA(a, wp[(kt * CT + ct) * 64 + lane], acc[ct]);
    }
#pragma unroll
    for (int ct = 0; ct < CT; ct++) {
        int jc = (w * CT + ct) * 16 + l15;
        char* base = outb + (jc >> 5) * 1024 + ((jc >> 3) & 3) * 256 + (jc & 7) * 2 + lhi * 64;
#pragma unroll
        for (int r = 0; r < 4; r++)
            *(bf16_t*)(base + r * 16) = (bf16_t)fmaxf(acc[ct][r], 0.0f);
    }
}

// ================= main persistent kernel =================
__attribute__((amdgpu_waves_per_eu(2, 2)))
__global__ void __launch_bounds__(512)
actor_main(const bf16_t* __restrict__ ws,
           const float* __restrict__ fc1_b, const float* __restrict__ fc2_b,
           const float* __restrict__ fc3_b, const float* __restrict__ fc4_b,
           const float* __restrict__ piW, const float* __restrict__ pib_p,
           float* __restrict__ out)
{
    __shared__ __align__(16) char smem[LDS_BYTES];
    const int tid = threadIdx.x;
    const int lane = tid & 63;
    const int w = tid >> 6;          // wave 0..7; owns cells [32w, 32w+32)
    const int l15 = lane & 15;
    const int lhi = lane >> 4;
    const int row0 = blockIdx.x * 16;
    const char* xpc = (const char*)(ws + XPAD_E) + (size_t)blockIdx.x * 25600;

    // h write base: cell = 32w + 16cg + l15 -> ktile w, k = 16cg + l15
    const int hwbase = HB + w * 1024 + 64 * lhi + 256 * (l15 >> 3) + 2 * (l15 & 7);

    // ---------- initial LDS fills (layer 1) ----------
    {
        const bf16x8* src = (const bf16x8*)(ws + W1HHL_E) + (w * 16) * 64 + lane;
#pragma unroll
        for (int f = 0; f < 16; f++)
            *(bf16x8*)(smem + WLDS + (w * 16 + f) * 1024 + lane * 16) = src[f * 64];
    }
    if (lane < 32) {
#pragma unroll
        for (int g = 0; g < 4; g++)
            *(bf16x8*)(smem + WIHL + (w * 4 + g) * 512 + lane * 16) =
                ((const bf16x8*)(ws + WIH1_E))[((w * 2 + 1) * 4 + g) * 32 + lane];
    }
    { int* z = (int*)(smem + HB); for (int q = tid; q < 2048; q += 512) z[q] = 0; }

    // ---------- layer-1 registers ----------
    bf16x8 whh_r[6][2][4];
    {
        const bf16x8* hr = (const bf16x8*)(ws + W1HHR_E) + w * (48 * 64) + lane;
#pragma unroll
        for (int kt = 0; kt < 6; kt++)
#pragma unroll
            for (int cg = 0; cg < 2; cg++)
#pragma unroll
                for (int g = 0; g < 4; g++)
                    whh_r[kt][cg][g] = hr[((kt * 2 + cg) * 4 + g) * 64];
    }
    float b1r[2][4];
    {
        const float* b1 = (const float*)(ws + BIAS1_E);
#pragma unroll
        for (int cg = 0; cg < 2; cg++)
#pragma unroll
            for (int g = 0; g < 4; g++)
                b1r[cg][g] = b1[g * 256 + w * 32 + cg * 16 + l15];
    }
    __syncthreads();

    // ===================== LSTM 1 =====================
    f32x4 cst[2];
#pragma unroll
    for (int cg = 0; cg < 2; cg++) cst[cg] = (f32x4){0.f, 0.f, 0.f, 0.f};

#pragma unroll 1
    for (int t = 0; t < 50; t++) {
        bf16x8 ax = zero8();
        if (lane < 32) ax = *(const bf16x8*)(xpc + t * 512 + lane * 16);
        bf16x4 hpk[2];
#pragma unroll
        for (int cg = 0; cg < 2; cg++) {
            f32x4 a0 = (f32x4){b1r[cg][0], b1r[cg][0], b1r[cg][0], b1r[cg][0]};
            f32x4 a1 = (f32x4){b1r[cg][1], b1r[cg][1], b1r[cg][1], b1r[cg][1]};
            f32x4 a2 = (f32x4){b1r[cg][2], b1r[cg][2], b1r[cg][2], b1r[cg][2]};
            f32x4 a3 = (f32x4){b1r[cg][3], b1r[cg][3], b1r[cg][3], b1r[cg][3]};
            // x contribution
#pragma unroll
            for (int g = 0; g < 4; g++) {
                bf16x8 wv = zero8();
                if (lane < 32) {
                    if (cg == 0) wv = ((const bf16x8*)(ws + WIH1_E))[((w * 2) * 4 + g) * 32 + lane];
                    else         wv = *(const bf16x8*)(smem + WIHL + (w * 4 + g) * 512 + lane * 16);
                }
                if (g == 0) a0 = MFMA(ax, wv, a0);
                else if (g == 1) a1 = MFMA(ax, wv, a1);
                else if (g == 2) a2 = MFMA(ax, wv, a2);
                else a3 = MFMA(ax, wv, a3);
            }
            // h contribution: reg ktiles 0..5
#pragma unroll
            for (int kt = 0; kt < 6; kt++) {
                bf16x8 ah = *(const bf16x8*)(smem + HB + kt * 1024 + lane * 16);
                a0 = MFMA(ah, whh_r[kt][cg][0], a0);
                a1 = MFMA(ah, whh_r[kt][cg][1], a1);
                a2 = MFMA(ah, whh_r[kt][cg][2], a2);
                a3 = MFMA(ah, whh_r[kt][cg][3], a3);
            }
            // LDS ktiles 6..7
#pragma unroll
            for (int kk = 0; kk < 2; kk++) {
                bf16x8 ah = *(const bf16x8*)(smem + HB + (6 + kk) * 1024 + lane * 16);
                const char* wbp = smem + WLDS + ((w * 2 + kk) * 2 + cg) * 4096 + lane * 16;
                a0 = MFMA(ah, *(const bf16x8*)(wbp), a0);
                a1 = MFMA(ah, *(const bf16x8*)(wbp + 1024), a1);
                a2 = MFMA(ah, *(const bf16x8*)(wbp + 2048), a2);
                a3 = MFMA(ah, *(const bf16x8*)(wbp + 3072), a3);
            }
#pragma unroll
            for (int r = 0; r < 4; r++) {
                float iv = sigm(a0[r]);
                float fv = sigm(a1[r]);
                float gv = tanh_fast(a2[r]);
                float ov = sigm(a3[r]);
                float c = fv * cst[cg][r] + iv * gv;
                cst[cg][r] = c;
                hpk[cg][r] = (bf16_t)(ov * tanh_fast(c));
            }
        }
        __syncthreads();
#pragma unroll
        for (int cg = 0; cg < 2; cg++)
#pragma unroll
            for (int r = 0; r < 4; r++)
                *(bf16_t*)(smem + hwbase + cg * 512 + r * 16) = hpk[cg][r];
        __syncthreads();
    }

    // ===================== MLP (scratch inside WLDS) =====================
    mlp8<8, 8>(smem + HB, smem + WLDS,
               (const bf16x8*)(ws + FC1_E) + w * 4096, fc1_b, w, lane);
    __syncthreads();
    mlp8<8, 32>(smem + WLDS, smem + WLDS + 32768,
                (const bf16x8*)(ws + FC2_E) + w * 16384, fc2_b, w, lane);
    __syncthreads();
    mlp8<4, 32>(smem + WLDS + 32768, smem + WLDS + 65536,
                (const bf16x8*)(ws + FC3_E) + w * 8192, fc3_b, w, lane);
    __syncthreads();
    mlp8<2, 16>(smem + WLDS + 65536, smem + WLDS + 81920,
                (const bf16x8*)(ws + FC4_E) + w * 2048, fc4_b, w, lane);
    __syncthreads();

    // ---------- hoist: base2 = bias2 + xmlp @ W2ihB^T ----------
    bf16x4 base2p[2][4];
    {
        f32x4 bacc[2][4];
        const float* b2 = (const float*)(ws + BIAS2_E);
#pragma unroll
        for (int cg = 0; cg < 2; cg++)
#pragma unroll
            for (int g = 0; g < 4; g++) {
                float bv = b2[g * 256 + w * 32 + cg * 16 + l15];
                bacc[cg][g] = (f32x4){bv, bv, bv, bv};
            }
        const bf16x8* wb = (const bf16x8*)(ws + W2IHB_E) + w * (64 * 64) + lane;
#pragma unroll 2
        for (int kt = 0; kt < 8; kt++) {
            bf16x8 a = *(const bf16x8*)(smem + WLDS + 81920 + kt * 1024 + lane * 16);
#pragma unroll
            for (int cg = 0; cg < 2; cg++)
#pragma unroll
                for (int g = 0; g < 4; g++)
                    bacc[cg][g] = MFMA(a, wb[((kt * 2 + cg) * 4 + g) * 64], bacc[cg][g]);
        }
#pragma unroll
        for (int cg = 0; cg < 2; cg++)
#pragma unroll
            for (int g = 0; g < 4; g++)
#pragma unroll
                for (int r = 0; r < 4; r++)
                    base2p[cg][g][r] = (bf16_t)bacc[cg][g][r];
    }
    __syncthreads();   // xmlp reads done before WLDS refill

    // ---------- refill LDS + regs for layer 2 ----------
    {
        const bf16x8* src = (const bf16x8*)(ws + W2HHL_E) + (w * 16) * 64 + lane;
#pragma unroll
        for (int f = 0; f < 16; f++)
            *(bf16x8*)(smem + WLDS + (w * 16 + f) * 1024 + lane * 16) = src[f * 64];
    }
    if (lane < 32) {
#pragma unroll
        for (int g = 0; g < 4; g++)
            *(bf16x8*)(smem + WIHL + (w * 4 + g) * 512 + lane * 16) =
                ((const bf16x8*)(ws + WIH2_E))[((w * 2 + 1) * 4 + g) * 32 + lane];
    }
    { int* z = (int*)(smem + HB); for (int q = tid; q < 2048; q += 512) z[q] = 0; }
    {
        const bf16x8* hr = (const bf16x8*)(ws + W2HHR_E) + w * (48 * 64) + lane;
#pragma unroll
        for (int kt = 0; kt < 6; kt++)
#pragma unroll
            for (int cg = 0; cg < 2; cg++)
#pragma unroll
                for (int g = 0; g < 4; g++)
                    whh_r[kt][cg][g] = hr[((kt * 2 + cg) * 4 + g) * 64];
    }
    float pw0, pw1, pw2, pw3;
    {
        const float4 p4 = *(const float4*)(piW + lane * 4);
        pw0 = p4.x; pw1 = p4.y; pw2 = p4.z; pw3 = p4.w;
    }
    const float pib = pib_p[0];
    // pi read addr: cells c0 = 4*lane of row rr
    const int pibyte = HB + (lane >> 3) * 1024 + 16 * 16 * ((lane >> 1) & 3) + 8 * (lane & 1);
    __syncthreads();

    // ===================== LSTM 2 + pi head =====================
#pragma unroll
    for (int cg = 0; cg < 2; cg++) cst[cg] = (f32x4){0.f, 0.f, 0.f, 0.f};

#pragma unroll 1
    for (int t = 0; t < 50; t++) {
        bf16x8 ax = zero8();
        if (lane < 32) ax = *(const bf16x8*)(xpc + t * 512 + lane * 16);
        bf16x4 hpk[2];
#pragma unroll
        for (int cg = 0; cg < 2; cg++) {
            f32x4 a0, a1, a2, a3;
#pragma unroll
            for (int r = 0; r < 4; r++) {
                a0[r] = (float)base2p[cg][0][r];
                a1[r] = (float)base2p[cg][1][r];
                a2[r] = (float)base2p[cg][2][r];
                a3[r] = (float)base2p[cg][3][r];
            }
#pragma unroll
            for (int g = 0; g < 4; g++) {
                bf16x8 wv = zero8();
                if (lane < 32) {
                    if (cg == 0) wv = ((const bf16x8*)(ws + WIH2_E))[((w * 2) * 4 + g) * 32 + lane];
                    else         wv = *(const bf16x8*)(smem + WIHL + (w * 4 + g) * 512 + lane * 16);
                }
                if (g == 0) a0 = MFMA(ax, wv, a0);
                else if (g == 1) a1 = MFMA(ax, wv, a1);
                else if (g == 2) a2 = MFMA(ax, wv, a2);
                else a3 = MFMA(ax, wv, a3);
            }
#pragma unroll
            for (int kt = 0; kt < 6; kt++) {
                bf16x8 ah = *(const bf16x8*)(smem + HB + kt * 1024 + lane * 16);
                a0 = MFMA(ah, whh_r[kt][cg][0], a0);
                a1 = MFMA(ah, whh_r[kt][cg][1], a1);
                a2 = MFMA(ah, whh_r[kt][cg][2], a2);
                a3 = MFMA(ah, whh_r[kt][cg][3], a3);
            }
#pragma unroll
            for (int kk = 0; kk < 2; kk++) {
                bf16x8 ah = *(const bf16x8*)(smem + HB + (6 + kk) * 1024 + lane * 16);
                const char* wbp = smem + WLDS + ((w * 2 + kk) * 2 + cg) * 4096 + lane * 16;
                a0 = MFMA(ah, *(const bf16x8*)(wbp), a0);
                a1 = MFMA(ah, *(const bf16x8*)(wbp + 1024), a1);
                a2 = MFMA(ah, *(const bf16x8*)(wbp + 2048), a2);
                a3 = MFMA(ah, *(const bf16x8*)(wbp + 3072), a3);
            }
#pragma unroll
            for (int r = 0; r < 4; r++) {
                float iv = sigm(a0[r]);
                float fv = sigm(a1[r]);
                float gv = tanh_fast(a2[r]);
                float ov = sigm(a3[r]);
                float c = fv * cst[cg][r] + iv * gv;
                cst[cg][r] = c;
                hpk[cg][r] = (bf16_t)(ov * tanh_fast(c));
            }
        }
        __syncthreads();
#pragma unroll
        for (int cg = 0; cg < 2; cg++)
#pragma unroll
            for (int r = 0; r < 4; r++)
                *(bf16_t*)(smem + hwbase + cg * 512 + r * 16) = hpk[cg][r];
        __syncthreads();

        // pi head: wave w reduces rows w and w+8
#pragma unroll
        for (int rr2 = 0; rr2 < 2; rr2++) {
            int rr = w + rr2 * 8;
            bf16x4 hv = *(const bf16x4*)(smem + pibyte + rr * 16);
            float s = (float)hv[0] * pw0 + (float)hv[1] * pw1 + (float)hv[2] * pw2 + (float)hv[3] * pw3;
            s += __shfl_xor(s, 1);
            s += __shfl_xor(s, 2);
            s += __shfl_xor(s, 4);
            s += __shfl_xor(s, 8);
            s += __shfl_xor(s, 16);
            s += __shfl_xor(s, 32);
            if (lane == 0) out[(size_t)(row0 + rr) * 50 + t] = tanh_fast(s + pib);
        }
    }
}

extern "C" void kernel_launch(void* const* d_in, const int* in_sizes, int n_in,
                              void* d_out, int out_size, void* d_ws, size_t ws_size,
                              hipStream_t stream) {
    (void)in_sizes; (void)n_in; (void)out_size; (void)ws_size;
    const float* state   = (const float*)d_in[0];
    const float* l1_Wih  = (const float*)d_in[1];
    const float* l1_Whh  = (const float*)d_in[2];
    const float* l1_bih  = (const float*)d_in[3];
    const float* l1_bhh  = (const float*)d_in[4];
    const float* fc1_W   = (const float*)d_in[5];
    const float* fc1_b   = (const float*)d_in[6];
    const float* fc2_W   = (const float*)d_in[7];
    const float* fc2_b   = (const float*)d_in[8];
    const float* fc3_W   = (const float*)d_in[9];
    const float* fc3_b   = (const float*)d_in[10];
    const float* fc4_W   = (const float*)d_in[11];
    const float* fc4_b   = (const float*)d_in[12];
    const float* l2_Wih  = (const float*)d_in[13];
    const float* l2_Whh  = (const float*)d_in[14];
    const float* l2_bih  = (const float*)d_in[15];
    const float* l2_bhh  = (const float*)d_in[16];
    const float* pi_W    = (const float*)d_in[17];
    const float* pi_b    = (const float*)d_in[18];
    bf16_t* ws = (bf16_t*)d_ws;
    float* out = (float*)d_out;

    pack_all<<<2048, 256, 0, stream>>>(state, l1_Wih, l1_Whh, l1_bih, l1_bhh,
                                       fc1_W, fc2_W, fc3_W, fc4_W,
                                       l2_Wih, l2_Whh, l2_bih, l2_bhh, ws);

    actor_main<<<256, 512, 0, stream>>>(ws, fc1_b, fc2_b, fc3_b, fc4_b,
                                        pi_W, pi_b, out);
}